// Round 2
// baseline (1199.532 us; speedup 1.0000x reference)
//
#include <hip/hip_runtime.h>

#define DIM 1024
#define NTOK 16384

typedef __attribute__((ext_vector_type(8))) _Float16 f16x8;
typedef __attribute__((ext_vector_type(4))) _Float16 f16x4;
typedef __attribute__((ext_vector_type(4))) float f32x4;

__device__ __forceinline__ void gload_lds16(const void* g, void* l) {
  __builtin_amdgcn_global_load_lds(
      (const __attribute__((address_space(1))) void*)g,
      (__attribute__((address_space(3))) void*)l, 16, 0, 0);
}

// ---------------------------------------------------------------------------
// f32 -> fp16 conversion of the input activations
// ---------------------------------------------------------------------------
__global__ __launch_bounds__(256) void cvt_kernel(const float* __restrict__ in,
                                                  _Float16* __restrict__ out) {
  const int i = blockIdx.x * 256 + threadIdx.x;
  float4 v = reinterpret_cast<const float4*>(in)[i];
  f16x4 o;
  o[0] = (_Float16)v.x;
  o[1] = (_Float16)v.y;
  o[2] = (_Float16)v.z;
  o[3] = (_Float16)v.w;
  *reinterpret_cast<f16x4*>(&out[(size_t)i * 4]) = o;
}

// ---------------------------------------------------------------------------
// W_eff[l][o][k] = fp16( qw[l,o,k] * scales[l,o,k/16] + sum_r lb[l,o,r]*la[l,r,k] )
// grid (4 k-tiles, 32 o-tiles, 18 layers), 256 threads: one k per thread
// ---------------------------------------------------------------------------
__global__ __launch_bounds__(256) void build_weff(const int* __restrict__ qw,
                                                  const float* __restrict__ scales,
                                                  const float* __restrict__ la,
                                                  const float* __restrict__ lb,
                                                  _Float16* __restrict__ W) {
  const int kt = blockIdx.x;  // 0..3
  const int ot = blockIdx.y;  // 0..31
  const int l = blockIdx.z;   // 0..17
  const int t = threadIdx.x;
  const int k = kt * 256 + t;

  float col[32];
#pragma unroll
  for (int r = 0; r < 32; ++r)
    col[r] = la[((size_t)l * 32 + r) * DIM + k];

  for (int oi = 0; oi < 32; ++oi) {
    const int o = ot * 32 + oi;
    const size_t ro = (size_t)l * DIM + o;
    const float* lbp = lb + ro * 32;
    float lora = 0.f;
#pragma unroll
    for (int r = 0; r < 32; ++r) lora = fmaf(lbp[r], col[r], lora);
    float w = (float)qw[ro * DIM + k] * scales[ro * 64 + (k >> 4)] + lora;
    W[ro * DIM + k] = (_Float16)w;
  }
}

// ---------------------------------------------------------------------------
// GEMM: OUT[n,o] = X[n,:] . W[o,:] + bias[o]  (+ReLU or +RES)
// 128x128 tile, BK=32, 4 waves of 64x64, mfma_f32_16x16x32_f16
// MODE 0: relu -> fp16     MODE 1: +res -> fp16     MODE 2: +res -> f32
// ---------------------------------------------------------------------------
template <int MODE>
__global__ __launch_bounds__(256) void qgemm(const _Float16* __restrict__ X,
                                             const _Float16* __restrict__ W,
                                             const float* __restrict__ bias,
                                             const _Float16* __restrict__ RES,
                                             void* __restrict__ OUT) {
  __shared__ _Float16 sA[128 * 32];
  __shared__ _Float16 sB[128 * 32];

  const int tid = threadIdx.x;
  const int wave = tid >> 6;
  const int lane = tid & 63;
  const int wm = wave >> 1;
  const int wn = wave & 1;
  const int bn = blockIdx.x;  // 8 n-tiles (fast: share X m-tile across L2)
  const int bm = blockIdx.y;  // 128 m-tiles

  f32x4 acc[4][4];
#pragma unroll
  for (int i = 0; i < 4; ++i)
#pragma unroll
    for (int j = 0; j < 4; ++j)
#pragma unroll
      for (int r = 0; r < 4; ++r) acc[i][j][r] = 0.f;

  const int srow = tid >> 2;   // 0..63: row within 64-row staging group
  const int schunk = tid & 3;  // 16B chunk within 64B row
  const _Float16* Xg = X + (size_t)bm * 128 * DIM + (size_t)srow * DIM + schunk * 8;
  const _Float16* Wg = W + (size_t)bn * 128 * DIM + (size_t)srow * DIM + schunk * 8;
  _Float16* sAw = &sA[(wave * 16) * 32];  // wave-uniform LDS base
  _Float16* sBw = &sB[(wave * 16) * 32];

  const int r16 = lane & 15;
  const int koff = lane >> 4;

  for (int kt = 0; kt < DIM / 32; ++kt) {
    const int k0 = kt * 32;
#pragma unroll
    for (int q = 0; q < 2; ++q) {
      gload_lds16(Xg + (size_t)q * 64 * DIM + k0, sAw + q * 64 * 32);
      gload_lds16(Wg + (size_t)q * 64 * DIM + k0, sBw + q * 64 * 32);
    }
    __syncthreads();

    f16x8 af[4], bf[4];
#pragma unroll
    for (int i = 0; i < 4; ++i) {
      af[i] = *reinterpret_cast<const f16x8*>(&sA[(wm * 64 + i * 16 + r16) * 32 + koff * 8]);
      bf[i] = *reinterpret_cast<const f16x8*>(&sB[(wn * 64 + i * 16 + r16) * 32 + koff * 8]);
    }
#pragma unroll
    for (int i = 0; i < 4; ++i)
#pragma unroll
      for (int j = 0; j < 4; ++j)
        acc[i][j] = __builtin_amdgcn_mfma_f32_16x16x32_f16(af[i], bf[j], acc[i][j], 0, 0, 0);
    __syncthreads();
  }

  // epilogue: C[row][col], col = lane&15, row = (lane>>4)*4 + r  (m89 layout)
  const int row0 = bm * 128 + wm * 64;
  const int col0 = bn * 128 + wn * 64;
  const int rg = (lane >> 4) * 4;
  float bv[4];
#pragma unroll
  for (int j = 0; j < 4; ++j) bv[j] = bias[col0 + j * 16 + r16];

#pragma unroll
  for (int i = 0; i < 4; ++i) {
#pragma unroll
    for (int j = 0; j < 4; ++j) {
      const int col = col0 + j * 16 + r16;
#pragma unroll
      for (int r = 0; r < 4; ++r) {
        const int row = row0 + i * 16 + rg + r;
        float v = acc[i][j][r] + bv[j];
        if (MODE == 0) {
          v = fmaxf(v, 0.f);
          ((_Float16*)OUT)[(size_t)row * DIM + col] = (_Float16)v;
        } else {
          v += (float)RES[(size_t)row * DIM + col];
          if (MODE == 1)
            ((_Float16*)OUT)[(size_t)row * DIM + col] = (_Float16)v;
          else
            ((float*)OUT)[(size_t)row * DIM + col] = v;
        }
      }
    }
  }
}

// ---------------------------------------------------------------------------
// LayerNorm over last dim (1024), one row per block, fp16 in/out
// ---------------------------------------------------------------------------
__global__ __launch_bounds__(256) void ln_kernel(const _Float16* __restrict__ in,
                                                 const float* __restrict__ g,
                                                 const float* __restrict__ b,
                                                 _Float16* __restrict__ out) {
  const int row = blockIdx.x;
  const int tid = threadIdx.x;
  const _Float16* rp = in + (size_t)row * DIM;

  f16x4 raw = reinterpret_cast<const f16x4*>(rp)[tid];
  float v0 = (float)raw[0], v1 = (float)raw[1], v2 = (float)raw[2], v3 = (float)raw[3];
  float s = v0 + v1 + v2 + v3;
  float sq = v0 * v0 + v1 * v1 + v2 * v2 + v3 * v3;
#pragma unroll
  for (int off = 32; off > 0; off >>= 1) {
    s += __shfl_down(s, off);
    sq += __shfl_down(sq, off);
  }
  __shared__ float ss[4], sq4[4];
  if ((tid & 63) == 0) {
    ss[tid >> 6] = s;
    sq4[tid >> 6] = sq;
  }
  __syncthreads();
  s = ss[0] + ss[1] + ss[2] + ss[3];
  sq = sq4[0] + sq4[1] + sq4[2] + sq4[3];
  const float mean = s * (1.f / DIM);
  const float var = sq * (1.f / DIM) - mean * mean;
  const float inv = rsqrtf(var + 1e-5f);

  float4 gv = reinterpret_cast<const float4*>(g)[tid];
  float4 bv = reinterpret_cast<const float4*>(b)[tid];
  f16x4 o;
  o[0] = (_Float16)((v0 - mean) * inv * gv.x + bv.x);
  o[1] = (_Float16)((v1 - mean) * inv * gv.y + bv.y);
  o[2] = (_Float16)((v2 - mean) * inv * gv.z + bv.z);
  o[3] = (_Float16)((v3 - mean) * inv * gv.w + bv.w);
  *reinterpret_cast<f16x4*>(&out[(size_t)row * DIM + tid * 4]) = o;
}

// ---------------------------------------------------------------------------

extern "C" void kernel_launch(void* const* d_in, const int* in_sizes, int n_in,
                              void* d_out, int out_size, void* d_ws, size_t ws_size,
                              hipStream_t stream) {
  const float* x = (const float*)d_in[0];
  const int* qw = (const int*)d_in[1];
  const float* scales = (const float*)d_in[2];
  const float* bias = (const float*)d_in[3];
  const float* la = (const float*)d_in[4];
  const float* lb = (const float*)d_in[5];
  const float* ln_g = (const float*)d_in[6];
  const float* ln_b = (const float*)d_in[7];

  char* ws = (char*)d_ws;
  const size_t WEFF_BYTES = (size_t)18 * DIM * DIM * 2;   // 37,748,736
  const size_t ACT_BYTES = (size_t)NTOK * DIM * 2;        // 33,554,432
  _Float16* Weff = (_Float16*)ws;
  _Float16* bufA = (_Float16*)(ws + WEFF_BYTES);
  _Float16* bufB = (_Float16*)(ws + WEFF_BYTES + ACT_BYTES);
  _Float16* bufC = (_Float16*)(ws + WEFF_BYTES + 2 * ACT_BYTES);

  cvt_kernel<<<NTOK * DIM / 1024, 256, 0, stream>>>(x, bufA);
  build_weff<<<dim3(4, 32, 18), 256, 0, stream>>>(qw, scales, la, lb, Weff);

  const dim3 ggrid(DIM / 128, NTOK / 128);  // n fastest: 8 blocks share an X tile
  for (int blk = 0; blk < 6; ++blk) {
    const int i0 = blk * 3;
    const size_t wstep = (size_t)DIM * DIM;
    qgemm<0><<<ggrid, 256, 0, stream>>>(bufA, Weff + (size_t)i0 * wstep,
                                        bias + i0 * DIM, nullptr, bufB);
    qgemm<0><<<ggrid, 256, 0, stream>>>(bufB, Weff + (size_t)(i0 + 1) * wstep,
                                        bias + (i0 + 1) * DIM, nullptr, bufC);
    if (blk < 5) {
      qgemm<1><<<ggrid, 256, 0, stream>>>(bufC, Weff + (size_t)(i0 + 2) * wstep,
                                          bias + (i0 + 2) * DIM, bufA, bufB);
      ln_kernel<<<NTOK, 256, 0, stream>>>(bufB, ln_g + blk * DIM, ln_b + blk * DIM, bufA);
    } else {
      qgemm<2><<<ggrid, 256, 0, stream>>>(bufC, Weff + (size_t)(i0 + 2) * wstep,
                                          bias + (i0 + 2) * DIM, bufA, d_out);
    }
  }
}

// Round 3
// 808.054 us; speedup vs baseline: 1.4845x; 1.4845x over previous
//
#include <hip/hip_runtime.h>

#define DIM 1024
#define NTOK 16384

typedef __attribute__((ext_vector_type(8))) _Float16 f16x8;
typedef __attribute__((ext_vector_type(4))) _Float16 f16x4;
typedef __attribute__((ext_vector_type(4))) float f32x4;

__device__ __forceinline__ void gload_lds16(const void* g, void* l) {
  __builtin_amdgcn_global_load_lds(
      (const __attribute__((address_space(1))) void*)g,
      (__attribute__((address_space(3))) void*)l, 16, 0, 0);
}

__device__ __forceinline__ f16x8 ldsr(const char* smem, int byteoff) {
  return *(const f16x8*)(smem + byteoff);
}

__device__ __forceinline__ f32x4 mfma16(f16x8 a, f16x8 b, f32x4 c) {
  return __builtin_amdgcn_mfma_f32_16x16x32_f16(a, b, c, 0, 0, 0);
}

// ---------------------------------------------------------------------------
// f32 -> fp16 conversion of the input activations
// ---------------------------------------------------------------------------
__global__ __launch_bounds__(256) void cvt_kernel(const float* __restrict__ in,
                                                  _Float16* __restrict__ out) {
  const int i = blockIdx.x * 256 + threadIdx.x;
  float4 v = reinterpret_cast<const float4*>(in)[i];
  f16x4 o;
  o[0] = (_Float16)v.x;
  o[1] = (_Float16)v.y;
  o[2] = (_Float16)v.z;
  o[3] = (_Float16)v.w;
  *reinterpret_cast<f16x4*>(&out[(size_t)i * 4]) = o;
}

// ---------------------------------------------------------------------------
// W_eff[l][o][k] = fp16( qw * scale + (lb @ la) )
// grid (4 kt, 32 ot, 18 l), 256 thr. la tile staged in LDS; int4 qw loads;
// f16x8 stores. Each thread: 8 consecutive k for 4 o's.
// ---------------------------------------------------------------------------
__global__ __launch_bounds__(256) void build_weff(const int* __restrict__ qw,
                                                  const float* __restrict__ scales,
                                                  const float* __restrict__ la,
                                                  const float* __restrict__ lb,
                                                  _Float16* __restrict__ W) {
  __shared__ float la_s[32][256];
  const int kt = blockIdx.x, ot = blockIdx.y, l = blockIdx.z;
  const int tid = threadIdx.x;

  for (int idx = tid; idx < 32 * 64; idx += 256) {
    const int r = idx >> 6, c4 = (idx & 63) * 4;
    *(float4*)&la_s[r][c4] =
        *(const float4*)&la[((size_t)l * 32 + r) * DIM + kt * 256 + c4];
  }
  __syncthreads();

  const int kq = tid & 31;   // 32 k8-positions
  const int os = tid >> 5;   // 8 o-sub
  const int k0 = kq * 8;     // local k
  const int kg = kt * 256 + k0;
  const size_t robase = (size_t)l * DIM + ot * 32 + os;  // o = +oi*8

  float acc[4][8];
#pragma unroll
  for (int a = 0; a < 4; ++a)
#pragma unroll
    for (int b = 0; b < 8; ++b) acc[a][b] = 0.f;

#pragma unroll 4
  for (int r = 0; r < 32; ++r) {
    const float4 lo = *(const float4*)&la_s[r][k0];
    const float4 hi = *(const float4*)&la_s[r][k0 + 4];
    const float la8[8] = {lo.x, lo.y, lo.z, lo.w, hi.x, hi.y, hi.z, hi.w};
#pragma unroll
    for (int oi = 0; oi < 4; ++oi) {
      const float lbv = lb[(robase + oi * 8) * 32 + r];
#pragma unroll
      for (int k = 0; k < 8; ++k) acc[oi][k] = fmaf(lbv, la8[k], acc[oi][k]);
    }
  }

#pragma unroll
  for (int oi = 0; oi < 4; ++oi) {
    const size_t ro = robase + oi * 8;
    const int4 q0 = *(const int4*)&qw[ro * DIM + kg];
    const int4 q1 = *(const int4*)&qw[ro * DIM + kg + 4];
    const float sc = scales[ro * 64 + (kg >> 4)];
    f16x8 o8;
    o8[0] = (_Float16)(fmaf((float)q0.x, sc, acc[oi][0]));
    o8[1] = (_Float16)(fmaf((float)q0.y, sc, acc[oi][1]));
    o8[2] = (_Float16)(fmaf((float)q0.z, sc, acc[oi][2]));
    o8[3] = (_Float16)(fmaf((float)q0.w, sc, acc[oi][3]));
    o8[4] = (_Float16)(fmaf((float)q1.x, sc, acc[oi][4]));
    o8[5] = (_Float16)(fmaf((float)q1.y, sc, acc[oi][5]));
    o8[6] = (_Float16)(fmaf((float)q1.z, sc, acc[oi][6]));
    o8[7] = (_Float16)(fmaf((float)q1.w, sc, acc[oi][7]));
    *(f16x8*)&W[ro * DIM + kg] = o8;
  }
}

// ---------------------------------------------------------------------------
// GEMM: OUT[n,o] = X[n,:] . W[o,:] + bias[o]  (+ReLU or +RES)
// 256x256 tile, BK=64, 8 waves (2M x 4N), 8-phase schedule (T2+T3+T4+T5),
// 128 KB double-buffered LDS, XOR-swizzled (pre-swizzled global source,
// swizzled ds_read). vmcnt(4) at phases 4/8 only.
// MODE 0: relu -> fp16   MODE 1: +res -> fp16   MODE 2: +res -> f32
// ---------------------------------------------------------------------------
#define ST_NONE ((void)0)
#define VM_NONE ((void)0)
#define VM4 asm volatile("s_waitcnt vmcnt(4)" ::: "memory")
#define VM0 asm volatile("s_waitcnt vmcnt(0)" ::: "memory")

// A-read: half = wm; row = FM*16 + r16; chunk = cks ^ (KS<<6)
#define RDA(BUF, FM, KS) \
  ldsr(smem, (((BUF)*2 + wm) << 14) + (((FM)*16 + r16) << 7) + (cks ^ ((KS) << 6)))
// B-read: half = wn>>1; row = (wn&1)*64 + FN*16 + r16
#define RDB(BUF, FN, KS)                                                        \
  ldsr(smem, 65536 + (((BUF)*2 + (wn >> 1)) << 14) +                            \
                 ((((wn & 1) * 64) + (FN)*16 + r16) << 7) + (cks ^ ((KS) << 6)))

#define PH(QQ, BUFC, STAGE, VMASM)                                          \
  {                                                                         \
    if ((QQ) == 0) {                                                        \
      _Pragma("unroll") for (int fn = 0; fn < 4; ++fn) {                    \
        bf[fn][0] = RDB(BUFC, fn, 0);                                       \
        bf[fn][1] = RDB(BUFC, fn, 1);                                       \
      }                                                                     \
    }                                                                       \
    f16x8 a00 = RDA(BUFC, 2 * (QQ), 0);                                     \
    f16x8 a01 = RDA(BUFC, 2 * (QQ), 1);                                     \
    f16x8 a10 = RDA(BUFC, 2 * (QQ) + 1, 0);                                 \
    f16x8 a11 = RDA(BUFC, 2 * (QQ) + 1, 1);                                 \
    STAGE;                                                                  \
    asm volatile("" ::: "memory");                                          \
    __builtin_amdgcn_s_barrier();                                           \
    asm volatile("s_waitcnt lgkmcnt(0)" ::: "memory");                      \
    __builtin_amdgcn_s_setprio(1);                                          \
    _Pragma("unroll") for (int fn = 0; fn < 4; ++fn) {                      \
      acc[2 * (QQ)][fn] = mfma16(a00, bf[fn][0], acc[2 * (QQ)][fn]);        \
      acc[2 * (QQ)][fn] = mfma16(a01, bf[fn][1], acc[2 * (QQ)][fn]);        \
      acc[2 * (QQ) + 1][fn] = mfma16(a10, bf[fn][0], acc[2 * (QQ) + 1][fn]); \
      acc[2 * (QQ) + 1][fn] = mfma16(a11, bf[fn][1], acc[2 * (QQ) + 1][fn]); \
    }                                                                       \
    __builtin_amdgcn_s_setprio(0);                                          \
    VMASM;                                                                  \
    asm volatile("" ::: "memory");                                          \
    __builtin_amdgcn_s_barrier();                                           \
  }

template <int MODE>
__global__ __launch_bounds__(512, 2) void qgemm(const _Float16* __restrict__ X,
                                                const _Float16* __restrict__ W,
                                                const float* __restrict__ bias,
                                                const _Float16* __restrict__ RES,
                                                void* __restrict__ OUT) {
  extern __shared__ char smem[];  // sA: [2buf][2half][128][64]f16 = 64KB; sB at +64KB

  const int tid = threadIdx.x;
  const int wave = tid >> 6;
  const int lane = tid & 63;
  const int wm = wave >> 2;  // 0..1 (M)
  const int wn = wave & 3;   // 0..3 (N)
  const int bn = blockIdx.x;
  const int bm = blockIdx.y;

  const int r16 = lane & 15;
  const int cks = ((lane >> 4) * 16) ^ ((lane & 7) << 4);  // swizzled chunk byte (ks=0)

  // staging: per wave 2 x gload_lds (1KB each) per half-tile; linear LDS dest,
  // inverse-swizzled global source column
  const int srl = lane >> 3;
  const int scs = ((lane & 7) ^ srl) << 3;  // f16-element column offset

  f32x4 acc[8][4];
#pragma unroll
  for (int i = 0; i < 8; ++i)
#pragma unroll
    for (int j = 0; j < 4; ++j)
#pragma unroll
      for (int r = 0; r < 4; ++r) acc[i][j][r] = 0.f;

  auto stageA = [&](int buf, int h, int t) {
    const _Float16* g =
        X + (size_t)(bm * 256 + h * 128 + wave * 16 + srl) * DIM + t * 64 + scs;
    char* d = smem + (((buf * 2 + h) << 14) + wave * 2048);
    gload_lds16(g, d);
    gload_lds16(g + 8 * DIM, d + 1024);
  };
  auto stageB = [&](int buf, int h, int t) {
    const _Float16* g =
        W + (size_t)(bn * 256 + h * 128 + wave * 16 + srl) * DIM + t * 64 + scs;
    char* d = smem + (65536 + ((buf * 2 + h) << 14) + wave * 2048);
    gload_lds16(g, d);
    gload_lds16(g + 8 * DIM, d + 1024);
  };

  // prologue: A(0),B(0) -> buf0; B(1) -> buf1
  stageA(0, 0, 0);
  stageA(0, 1, 0);
  stageB(0, 0, 0);
  stageB(0, 1, 0);
  stageB(1, 0, 1);
  stageB(1, 1, 1);
  VM4;  // A(0),B(0) landed; B(1) may fly
  __builtin_amdgcn_s_barrier();

  f16x8 bf[4][2];

  for (int i = 0; i < 7; ++i) {
    const int t0 = 2 * i, t1 = 2 * i + 1;
    // phases 1-4: compute K-tile t0 from buf0
    PH(0, 0, stageA(1, 0, t1), VM_NONE)
    PH(1, 0, stageA(1, 1, t1), VM_NONE)
    PH(2, 0, stageB(0, 0, t0 + 2), VM_NONE)
    PH(3, 0, stageB(0, 1, t0 + 2), VM4)
    // phases 5-8: compute K-tile t1 from buf1
    PH(0, 1, stageA(0, 0, t0 + 2), VM_NONE)
    PH(1, 1, stageA(0, 1, t0 + 2), VM_NONE)
    PH(2, 1, stageB(1, 0, t1 + 2), VM_NONE)
    PH(3, 1, stageB(1, 1, t1 + 2), VM4)
  }
  // tail: t0=14, t1=15 — only A(15) still needs staging
  PH(0, 0, stageA(1, 0, 15), VM_NONE)
  PH(1, 0, stageA(1, 1, 15), VM_NONE)
  PH(2, 0, ST_NONE, VM_NONE)
  PH(3, 0, ST_NONE, VM0)
  PH(0, 1, ST_NONE, VM_NONE)
  PH(1, 1, ST_NONE, VM_NONE)
  PH(2, 1, ST_NONE, VM_NONE)
  PH(3, 1, ST_NONE, VM_NONE)

  // epilogue: C col = lane&15, row = (lane>>4)*4 + r
  const int row0 = bm * 256 + wm * 128;
  const int col0 = bn * 256 + wn * 64;
  const int rg = (lane >> 4) * 4;
  float bv[4];
#pragma unroll
  for (int fn = 0; fn < 4; ++fn) bv[fn] = bias[col0 + fn * 16 + r16];

#pragma unroll
  for (int fm = 0; fm < 8; ++fm) {
#pragma unroll
    for (int fn = 0; fn < 4; ++fn) {
      const int col = col0 + fn * 16 + r16;
#pragma unroll
      for (int r = 0; r < 4; ++r) {
        const int row = row0 + fm * 16 + rg + r;
        float v = acc[fm][fn][r] + bv[fn];
        if (MODE == 0) {
          v = fmaxf(v, 0.f);
          ((_Float16*)OUT)[(size_t)row * DIM + col] = (_Float16)v;
        } else {
          v += (float)RES[(size_t)row * DIM + col];
          if (MODE == 1)
            ((_Float16*)OUT)[(size_t)row * DIM + col] = (_Float16)v;
          else
            ((float*)OUT)[(size_t)row * DIM + col] = v;
        }
      }
    }
  }
}

// ---------------------------------------------------------------------------
// LayerNorm over last dim (1024), one row per block, fp16 in/out
// ---------------------------------------------------------------------------
__global__ __launch_bounds__(256) void ln_kernel(const _Float16* __restrict__ in,
                                                 const float* __restrict__ g,
                                                 const float* __restrict__ b,
                                                 _Float16* __restrict__ out) {
  const int row = blockIdx.x;
  const int tid = threadIdx.x;
  const _Float16* rp = in + (size_t)row * DIM;

  f16x4 raw = reinterpret_cast<const f16x4*>(rp)[tid];
  float v0 = (float)raw[0], v1 = (float)raw[1], v2 = (float)raw[2], v3 = (float)raw[3];
  float s = v0 + v1 + v2 + v3;
  float sq = v0 * v0 + v1 * v1 + v2 * v2 + v3 * v3;
#pragma unroll
  for (int off = 32; off > 0; off >>= 1) {
    s += __shfl_down(s, off);
    sq += __shfl_down(sq, off);
  }
  __shared__ float ss[4], sq4[4];
  if ((tid & 63) == 0) {
    ss[tid >> 6] = s;
    sq4[tid >> 6] = sq;
  }
  __syncthreads();
  s = ss[0] + ss[1] + ss[2] + ss[3];
  sq = sq4[0] + sq4[1] + sq4[2] + sq4[3];
  const float mean = s * (1.f / DIM);
  const float var = sq * (1.f / DIM) - mean * mean;
  const float inv = rsqrtf(var + 1e-5f);

  float4 gv = reinterpret_cast<const float4*>(g)[tid];
  float4 bv = reinterpret_cast<const float4*>(b)[tid];
  f16x4 o;
  o[0] = (_Float16)((v0 - mean) * inv * gv.x + bv.x);
  o[1] = (_Float16)((v1 - mean) * inv * gv.y + bv.y);
  o[2] = (_Float16)((v2 - mean) * inv * gv.z + bv.z);
  o[3] = (_Float16)((v3 - mean) * inv * gv.w + bv.w);
  *reinterpret_cast<f16x4*>(&out[(size_t)row * DIM + tid * 4]) = o;
}

// ---------------------------------------------------------------------------

extern "C" void kernel_launch(void* const* d_in, const int* in_sizes, int n_in,
                              void* d_out, int out_size, void* d_ws, size_t ws_size,
                              hipStream_t stream) {
  const float* x = (const float*)d_in[0];
  const int* qw = (const int*)d_in[1];
  const float* scales = (const float*)d_in[2];
  const float* bias = (const float*)d_in[3];
  const float* la = (const float*)d_in[4];
  const float* lb = (const float*)d_in[5];
  const float* ln_g = (const float*)d_in[6];
  const float* ln_b = (const float*)d_in[7];

  char* ws = (char*)d_ws;
  const size_t WEFF_BYTES = (size_t)18 * DIM * DIM * 2;
  const size_t ACT_BYTES = (size_t)NTOK * DIM * 2;
  _Float16* Weff = (_Float16*)ws;
  _Float16* bufA = (_Float16*)(ws + WEFF_BYTES);
  _Float16* bufB = (_Float16*)(ws + WEFF_BYTES + ACT_BYTES);
  _Float16* bufC = (_Float16*)(ws + WEFF_BYTES + 2 * ACT_BYTES);

  const int LDS_BYTES = 131072;
  (void)hipFuncSetAttribute((const void*)&qgemm<0>,
                            hipFuncAttributeMaxDynamicSharedMemorySize, LDS_BYTES);
  (void)hipFuncSetAttribute((const void*)&qgemm<1>,
                            hipFuncAttributeMaxDynamicSharedMemorySize, LDS_BYTES);
  (void)hipFuncSetAttribute((const void*)&qgemm<2>,
                            hipFuncAttributeMaxDynamicSharedMemorySize, LDS_BYTES);

  cvt_kernel<<<NTOK * DIM / 1024, 256, 0, stream>>>(x, bufA);
  build_weff<<<dim3(4, 32, 18), 256, 0, stream>>>(qw, scales, la, lb, Weff);

  const dim3 ggrid(DIM / 256, NTOK / 256);  // (4, 64) = 256 blocks, 1/CU
  for (int blk = 0; blk < 6; ++blk) {
    const int i0 = blk * 3;
    const size_t wstep = (size_t)DIM * DIM;
    qgemm<0><<<ggrid, 512, LDS_BYTES, stream>>>(bufA, Weff + (size_t)i0 * wstep,
                                                bias + i0 * DIM, nullptr, bufB);
    qgemm<0><<<ggrid, 512, LDS_BYTES, stream>>>(bufB, Weff + (size_t)(i0 + 1) * wstep,
                                                bias + (i0 + 1) * DIM, nullptr, bufC);
    if (blk < 5) {
      qgemm<1><<<ggrid, 512, LDS_BYTES, stream>>>(bufC, Weff + (size_t)(i0 + 2) * wstep,
                                                  bias + (i0 + 2) * DIM, bufA, bufB);
      ln_kernel<<<NTOK, 256, 0, stream>>>(bufB, ln_g + blk * DIM, ln_b + blk * DIM, bufA);
    } else {
      qgemm<2><<<ggrid, 512, LDS_BYTES, stream>>>(bufC, Weff + (size_t)(i0 + 2) * wstep,
                                                  bias + (i0 + 2) * DIM, bufA, d_out);
    }
  }
}